// Round 8
// baseline (297.184 us; speedup 1.0000x reference)
//
#include <hip/hip_runtime.h>

#define A_ALLELES 4096
#define CCH 12     // input channels
#define LW 32      // read window length
#define DH 32      // hidden dim
#define RDF (CCH * LW)          // floats per read = 384
#define PAIRF (2 * RDF)         // floats per read-pair = 768 (3072 B)
#define NSLOT 3                 // LDS ring slots (pairs) per wave

typedef __attribute__((ext_vector_type(8)))  short bf16x8;   // 4 VGPRs
typedef __attribute__((ext_vector_type(16))) float f32x16;   // 16 VGPRs

// pack two fp32 -> two bf16 (round-half-up; differs from RNE only on ties)
__device__ inline unsigned pk2(float fa, float fb) {
    const unsigned a = __float_as_uint(fa), b = __float_as_uint(fb);
    return ((a + 0x8000u) >> 16) | ((b + 0x8000u) & 0xffff0000u);
}

// async global->LDS, width 16 (HW-verified m97): lane i -> lds + i*16.
__device__ inline void gld16(const float* g, float* lds) {
    __builtin_amdgcn_global_load_lds(
        (const __attribute__((address_space(1))) void*)g,
        (__attribute__((address_space(3))) void*)lds, 16, 0, 0);
}

// ---------------------------------------------------------------------------
// Kernel 1: exclusive prefix-sum of the two per-allele read-count arrays.
// ---------------------------------------------------------------------------
__global__ __launch_bounds__(256) void scan_kernel(
    const int* __restrict__ c0, const int* __restrict__ c1,
    int* __restrict__ o0, int* __restrict__ o1)
{
    const int* c = (blockIdx.x == 0) ? c0 : c1;
    int*       o = (blockIdx.x == 0) ? o0 : o1;

    __shared__ int part[256];
    const int tid  = threadIdx.x;
    const int base = tid * 16;

    int loc[16];
    int s = 0;
#pragma unroll
    for (int i = 0; i < 16; ++i) { loc[i] = c[base + i]; s += loc[i]; }
    part[tid] = s;
    __syncthreads();

    for (int st = 1; st < 256; st <<= 1) {
        int v = (tid >= st) ? part[tid - st] : 0;
        __syncthreads();
        part[tid] += v;
        __syncthreads();
    }

    int excl = (tid == 0) ? 0 : part[tid - 1];
#pragma unroll
    for (int i = 0; i < 16; ++i) { o[base + i] = excl; excl += loc[i]; }
}

// ---------------------------------------------------------------------------
// Kernel 2: 32x32x16 bf16 MFMA, one MFMA per read. Reads staged in PAIRS:
// 3 x global_load_lds(width16) per pair (lane scatter i*16 -> contiguous
// 3072B slot) into a 3-pair LDS ring per wave. Ordering enforced by inline
// asm "s_waitcnt vmcnt(6)" with "memory" clobber (6 carried + 3 new = 9
// outstanding; waits exactly the oldest pair). Clamped duplicate tail
// prefetches keep the count constant. B-frags via 8 ds_read_b32/read
// (bank = l, 2-way alias = free). A = W hoisted, bias via C operand,
// D[row=(reg&3)+8*(reg>>2)+4*h][col=l] (HW-verified). Epilogue: shfl over
// l, fold 1/(32*depth) + W2 head, 2 atomics per (allele,src).
// ---------------------------------------------------------------------------
__global__ __launch_bounds__(256, 4) void main_kernel(
    const float* __restrict__ t0, const float* __restrict__ t1,
    const float* __restrict__ W0, const float* __restrict__ b0,
    const float* __restrict__ W1, const float* __restrict__ b1,
    const float* __restrict__ W2, const float* __restrict__ b2,
    const int*  __restrict__ cnt0, const int* __restrict__ cnt1,
    const float* __restrict__ dm0, const float* __restrict__ dm1,
    const int*  __restrict__ offs0, const int* __restrict__ offs1,
    float* __restrict__ out)
{
    __shared__ float stage[4][NSLOT][PAIRF];   // 4 waves x 3 pair-slots x 3072B
    __shared__ float sW2[2 * 2 * DH];
    __shared__ float sB2[2];

    const int tid = threadIdx.x;
    if (tid < 2 * 2 * DH) sW2[tid] = W2[tid];
    if (tid < 2) sB2[tid] = b2[tid];
    __syncthreads();                     // once; main loop is barrier-free

    const int w    = tid >> 6;
    const int lane = tid & 63;
    const int src  = blockIdx.x >> 10;                  // block-uniform
    const int a    = ((blockIdx.x & 1023) << 2) | w;    // 0..4095

    const float* __restrict__ tens = src ? t1 : t0;
    const int*   __restrict__ cnt  = src ? cnt1 : cnt0;
    const int*   __restrict__ offs = src ? offs1 : offs0;
    const float* __restrict__ dm   = src ? dm1 : dm0;
    const float* __restrict__ gW   = src ? W1 : W0;
    const float* __restrict__ gB   = src ? b1 : b0;

    const int l = lane & 31;             // B column / D column
    const int h = lane >> 5;             // k-half selector

    // ---- hoisted: A fragment from W: A[m=d=l][k=h*8+j], zero k>=12 -------
    union { bf16x8 v; unsigned u[4]; } Af;
#pragma unroll
    for (int p = 0; p < 4; ++p) {
        const int c0 = h * 8 + 2 * p, c1 = c0 + 1;
        const float f0 = (c0 < CCH) ? gW[l * CCH + c0] : 0.f;
        const float f1 = (c1 < CCH) ? gW[l * CCH + c1] : 0.f;
        Af.u[p] = pk2(f0, f1);
    }
    // ---- hoisted: bias via C operand: C[row=d][col] = b[d] ---------------
    f32x16 cb;
#pragma unroll
    for (int reg = 0; reg < 16; ++reg)
        cb[reg] = gB[(reg & 3) + 8 * (reg >> 2) + 4 * h];

    const int n     = cnt[a];
    const int start = offs[a];
    const float* rb = tens + (size_t)start * RDF;

    const int lane4 = lane * 4;          // 16 B per lane, in floats

    // LDS read offsets (floats) within one READ: value (c, l).
    const int ldsLo = h * 8 * LW + l;            // c = h*8 + j     (+ j*32)
    const int ldsHi = (h ? 8 : 4) * LW + l;      // c = 4..7 / dead (+ j*32)

    float acc[16];
#pragma unroll
    for (int reg = 0; reg < 16; ++reg) acc[reg] = 0.f;

#define STAGE_PAIR(slot, pr) do {                                     \
        const float* g_ = rb + (size_t)(pr) * PAIRF + lane4;          \
        gld16(g_,       &stage[w][slot][0]);                          \
        gld16(g_ + 256, &stage[w][slot][256]);                        \
        gld16(g_ + 512, &stage[w][slot][512]);  } while (0)

#define READ8_PACK(ptr, Bf) do {                                      \
        float v0 = (ptr)[ldsLo +  0], v1 = (ptr)[ldsLo + 32];         \
        float v2 = (ptr)[ldsLo + 64], v3 = (ptr)[ldsLo + 96];         \
        float v4 = (ptr)[ldsHi +  0], v5 = (ptr)[ldsHi + 32];         \
        float v6 = (ptr)[ldsHi + 64], v7 = (ptr)[ldsHi + 96];         \
        Bf.u[0] = pk2(v0, v1); Bf.u[1] = pk2(v2, v3);                 \
        Bf.u[2] = pk2(v4, v5); Bf.u[3] = pk2(v6, v7); } while (0)

    const int P = n >> 1;                // pairs (n is 16/24 here: even)
    if (P > 0) {
        STAGE_PAIR(0, 0);
        STAGE_PAIR(1, (P > 1) ? 1 : 0);

        int s = 0;
        for (int p = 0; p < P; ++p) {
            const int rp = (p + 2 < P) ? (p + 2) : (P - 1);   // clamped dup
            int sp = s + 2; if (sp >= NSLOT) sp -= NSLOT;
            STAGE_PAIR(sp, rp);

            // wait until pair p's 3 DMAs land (exactly 6 newer outstanding).
            // asm + "memory" clobber: compiler cannot hoist the ds_reads
            // above this nor sink the DMA issues below it.
            asm volatile("s_waitcnt vmcnt(6)" ::: "memory");

            const float* s0 = &stage[w][s][0];     // read 2p
            const float* s1 = s0 + RDF;            // read 2p+1

            union { bf16x8 v; unsigned u[4]; } Bf0, Bf1;
            READ8_PACK(s0, Bf0);
            READ8_PACK(s1, Bf1);

            const f32x16 D0 = __builtin_amdgcn_mfma_f32_32x32x16_bf16(
                Af.v, Bf0.v, cb, 0, 0, 0);
            const f32x16 D1 = __builtin_amdgcn_mfma_f32_32x32x16_bf16(
                Af.v, Bf1.v, cb, 0, 0, 0);
#pragma unroll
            for (int reg = 0; reg < 16; ++reg)
                acc[reg] += fmaxf(D0[reg], 0.f) + fmaxf(D1[reg], 0.f);

            ++s; if (s >= NSLOT) s = 0;
        }
    }
    if (n & 1) {   // generality tail (dead here): direct register path
        const float* q = rb + (size_t)(n - 1) * RDF;
        float v0 = q[ldsLo +  0], v1 = q[ldsLo + 32];
        float v2 = q[ldsLo + 64], v3 = q[ldsLo + 96];
        float v4 = q[ldsHi +  0], v5 = q[ldsHi + 32];
        float v6 = q[ldsHi + 64], v7 = q[ldsHi + 96];
        union { bf16x8 v; unsigned u[4]; } Bf;
        Bf.u[0] = pk2(v0, v1); Bf.u[1] = pk2(v2, v3);
        Bf.u[2] = pk2(v4, v5); Bf.u[3] = pk2(v6, v7);
        const f32x16 D = __builtin_amdgcn_mfma_f32_32x32x16_bf16(
            Af.v, Bf.v, cb, 0, 0, 0);
#pragma unroll
        for (int reg = 0; reg < 16; ++reg) acc[reg] += fmaxf(D[reg], 0.f);
    }

    // reduce over l (cols): masks 1..16 stay within each 32-lane half
#pragma unroll
    for (int reg = 0; reg < 16; ++reg) {
#pragma unroll
        for (int mm = 1; mm < 32; mm <<= 1)
            acc[reg] += __shfl_xor(acc[reg], mm, 64);
    }

    const float scale = 1.f / (32.f * dm[a]);
    float c0s = 0.f, c1s = 0.f;
#pragma unroll
    for (int reg = 0; reg < 16; ++reg) {
        const int d = (reg & 3) + 8 * (reg >> 2) + 4 * h;
        const float pv = acc[reg] * scale;     // pooled[a, src*32 + d]
        c0s = fmaf(pv, sW2[0 * 2 * DH + src * DH + d], c0s);
        c1s = fmaf(pv, sW2[1 * 2 * DH + src * DH + d], c1s);
    }
    // combine the two h-halves (each held 16 of the 32 d's)
    c0s += __shfl_xor(c0s, 32, 64);
    c1s += __shfl_xor(c1s, 32, 64);

    if (lane == 0) {
        if (src == 0) { c0s += sB2[0]; c1s += sB2[1]; }
        atomicAdd(&out[a * 2 + 0], c0s);
        atomicAdd(&out[a * 2 + 1], c1s);
    }
#undef STAGE_PAIR
#undef READ8_PACK
}

extern "C" void kernel_launch(void* const* d_in, const int* in_sizes, int n_in,
                              void* d_out, int out_size, void* d_ws, size_t ws_size,
                              hipStream_t stream) {
    const float* t0  = (const float*)d_in[0];
    const float* t1  = (const float*)d_in[1];
    const float* W0  = (const float*)d_in[2];
    const float* b0  = (const float*)d_in[3];
    const float* W1  = (const float*)d_in[4];
    const float* b1  = (const float*)d_in[5];
    const float* W2  = (const float*)d_in[6];
    const float* b2  = (const float*)d_in[7];
    const int*  cnt0 = (const int*)d_in[8];
    const int*  cnt1 = (const int*)d_in[9];
    // d_in[10] = numAllelesPerSite (unused by the reference math)
    const float* dm0 = (const float*)d_in[11];
    const float* dm1 = (const float*)d_in[12];

    int* offs0 = (int*)d_ws;
    int* offs1 = offs0 + A_ALLELES;

    hipMemsetAsync(d_out, 0, (size_t)out_size * sizeof(float), stream);
    scan_kernel<<<2, 256, 0, stream>>>(cnt0, cnt1, offs0, offs1);

    main_kernel<<<2048, 256, 0, stream>>>(
        t0, t1, W0, b0, W1, b1, W2, b2,
        cnt0, cnt1, dm0, dm1, offs0, offs1, (float*)d_out);
}